// Round 15
// baseline (192.285 us; speedup 1.0000x reference)
//
#include <hip/hip_runtime.h>
#include <stdint.h>

typedef float f32x4 __attribute__((ext_vector_type(4)));
typedef float f32x16 __attribute__((ext_vector_type(16)));
typedef short bf16x8 __attribute__((ext_vector_type(8)));
typedef unsigned short ushort8 __attribute__((ext_vector_type(8)));

__device__ __forceinline__ unsigned short f2bf(float x) {
  union { float f; uint32_t u; } c; c.f = x;
  return (unsigned short)((c.u + 0x8000u) >> 16);
}
__device__ __forceinline__ float bf2f(unsigned short u) {
  union { uint32_t u; float f; } c; c.u = ((uint32_t)u) << 16;
  return c.f;
}

// Granule layout: per tile 131072 shorts = [kt(32)][kb4(4)][r(128)][e(8)]
// MFMA 32x32x16 frag read (lane l, ki): r = base+(l&31), kb4 = ki*2+(l>>5)
//   -> consecutive lanes touch consecutive 16B (LDS conflict-free / gmem coalesced).
// score15 consumes TWO granules (kt=2t, 2t+1) per barrier pair (BK=64), with a
// per-block K-offset stagger to de-correlate co-resident blocks' pipeline phases.

// ---------------- fused prep: W_enc granules ; dh ; mask compaction ----------------
__global__ void prep_fused_k(const float* __restrict__ W, unsigned short* __restrict__ Wt,
                             const float* __restrict__ dec, const float* __restrict__ Wd,
                             float* __restrict__ dh, const int* __restrict__ mask,
                             int* __restrict__ rows, int* __restrict__ cnt,
                             float* __restrict__ wout) {
  if (blockIdx.x < 512) {
    int t = blockIdx.x * 256 + threadIdx.x;      // 131072
    int d  = t >> 7;                              // 0..1023 (output dim = granule row)
    int c0 = (t & 127) << 3;
    const float* src = W + ((size_t)d << 10) + c0;
    f32x4 f0 = *(const f32x4*)src;
    f32x4 f1 = *(const f32x4*)(src + 4);
    ushort8 u;
    u[0]=f2bf(f0[0]); u[1]=f2bf(f0[1]); u[2]=f2bf(f0[2]); u[3]=f2bf(f0[3]);
    u[4]=f2bf(f1[0]); u[5]=f2bf(f1[1]); u[6]=f2bf(f1[2]); u[7]=f2bf(f1[3]);
    int nt = d >> 7, r = d & 127;
    int kt = c0 >> 6, kb = (c0 & 63) >> 3;
    *(ushort8*)(Wt + ((size_t)nt << 17) + (kt << 13) + ((kb * 128 + r) << 3)) = u;
  } else if (blockIdx.x < 640) {
    __shared__ float sdec[1024];
    int bb = blockIdx.x - 512;
    int b = bb >> 2;
    for (int i = threadIdx.x; i < 1024; i += 256) sdec[i] = dec[(b << 10) + i];
    __syncthreads();
    int d = ((bb & 3) << 8) + threadIdx.x;
    const float* wr = Wd + ((size_t)d << 10);
    float a = 0.f;
    for (int k = 0; k < 1024; k += 4) {
      f32x4 wv = *(const f32x4*)(wr + k);
      f32x4 xv = *(const f32x4*)(&sdec[k]);
      a += wv[0]*xv[0] + wv[1]*xv[1] + wv[2]*xv[2] + wv[3]*xv[3];
    }
    dh[(b << 10) + d] = a;
  } else {
    int b = blockIdx.x - 640, tid = threadIdx.x;
    int lane = tid & 63, wvx = tid >> 6;
    int mloc[8]; int c = 0;
    #pragma unroll
    for (int ii = 0; ii < 8; ++ii) {
      int s = tid * 8 + ii;
      int m = mask[(b << 11) + s];
      mloc[ii] = m; c += m;
      wout[(b << 11) + s] = 0.f;
    }
    int inc = c;
    #pragma unroll
    for (int off = 1; off < 64; off <<= 1) {
      int nn = __shfl_up(inc, off);
      if (lane >= off) inc += nn;
    }
    __shared__ int wsum[4];
    if (lane == 63) wsum[wvx] = inc;
    __syncthreads();
    int base = 0;
    for (int w = 0; w < wvx; ++w) base += wsum[w];
    int idx = base + inc - c;
    #pragma unroll
    for (int ii = 0; ii < 8; ++ii) {
      if (mloc[ii]) { rows[(b << 11) + idx] = tid * 8 + ii; ++idx; }
    }
    if (tid == 0) cnt[b] = wsum[0] + wsum[1] + wsum[2] + wsum[3];
  }
}

// ---------------- pack: enc rows -> granules, LDS-transposed so BOTH sides coalesce ----------------
__global__ void pack8_k(const float* __restrict__ enc, const int* __restrict__ rows,
                        const int* __restrict__ cnt, unsigned short* __restrict__ encP) {
  int b = blockIdx.x >> 4, mt = blockIdx.x & 15;
  int n = cnt[b];
  if (mt * 128 >= n) return;
  __shared__ int sr[128];
  __shared__ unsigned short T[128 * 64];   // bf16 tile, col-block swizzled
  int tid = threadIdx.x;
  if (tid < 128) {
    int i = mt * 128 + tid; if (i >= n) i = n - 1;
    sr[tid] = rows[(b << 11) + i];
  }
  __syncthreads();
  unsigned short* dst = encP + (((size_t)(b * 16 + mt)) << 17);
  for (int kt = 0; kt < 16; ++kt) {
    #pragma unroll
    for (int p = 0; p < 4; ++p) {
      int id = p * 256 + tid;            // 0..1023
      int r = id >> 3, cseg = id & 7;    // cseg: 8-col block
      const float* src = enc + (((size_t)(b << 11) + sr[r]) << 10) + (kt << 6) + (cseg << 3);
      f32x4 f0 = *(const f32x4*)src;
      f32x4 f1 = *(const f32x4*)(src + 4);
      ushort8 u;
      u[0]=f2bf(f0[0]); u[1]=f2bf(f0[1]); u[2]=f2bf(f0[2]); u[3]=f2bf(f0[3]);
      u[4]=f2bf(f1[0]); u[5]=f2bf(f1[1]); u[6]=f2bf(f1[2]); u[7]=f2bf(f1[3]);
      *(ushort8*)&T[(r << 6) + ((cseg ^ (r & 7)) << 3)] = u;
    }
    __syncthreads();
    unsigned short* g = dst + (kt << 13);
    #pragma unroll
    for (int p = 0; p < 4; ++p) {
      int blk = p * 256 + tid;           // 0..1023
      int kb = blk >> 7, r = blk & 127;
      ushort8 u = *(const ushort8*)&T[(r << 6) + ((kb ^ (r & 7)) << 3)];
      *(ushort8*)(g + (blk << 3)) = u;
    }
    __syncthreads();
  }
}

// ---------------- main fused GEMM: BK=64, ring-3 LDS, B-dedup regs, K-stagger + setprio ----------------
__global__ __launch_bounds__(256, 3) void score15_k(
    const unsigned short* __restrict__ encP, const unsigned short* __restrict__ Wt,
    const float* __restrict__ dh, const float* __restrict__ v,
    const int* __restrict__ cnt, float* __restrict__ pscores)
{
  // XCD swizzle: 8 consecutive same-XCD ids share one A-tile (sweep nt fastest)
  int L  = (blockIdx.x & 7) * 512 + (blockIdx.x >> 3);   // bijective, 4096 = 8*512
  int b  = L >> 7, mt = (L >> 3) & 15, nt = L & 7;
  int n  = cnt[b];
  if (mt * 128 >= n) return;

  __shared__ __align__(16) unsigned short AS[3][8192];   // 3 x 16 KB (A, 2 granules/slot)

  int tid  = threadIdx.x;
  int lane = tid & 63;
  int wv   = tid >> 6;                  // wave owns cols wv*32..wv*32+31
  int l31 = lane & 31, l5 = lane >> 5;
  int st   = (blockIdx.x >> 3) & 15;    // per-block K-phase stagger

#define KT(T) ((st + (T)) & 15)

  const unsigned short* aT = encP + (((size_t)(b * 16 + mt)) << 17);
  const unsigned short* bT = Wt + ((size_t)nt << 17);

  // per-granule frag offsets (elems): kb4 = ki*2+l5
  int offA[4][2], boff[2];
  #pragma unroll
  for (int mf = 0; mf < 4; ++mf) {
    int r = mf * 32 + l31;
    #pragma unroll
    for (int ki = 0; ki < 2; ++ki)
      offA[mf][ki] = (((ki * 2 + l5) << 7) + r) << 3;
  }
  {
    int r = wv * 32 + l31;
    #pragma unroll
    for (int ki = 0; ki < 2; ++ki)
      boff[ki] = (((ki * 2 + l5) << 7) + r) << 3;
  }

  f32x16 acc[4];
  #pragma unroll
  for (int i = 0; i < 4; ++i)
    #pragma unroll
    for (int e = 0; e < 16; ++e)
      acc[i][e] = 0.f;

  // stage both granules of K-step t into slot (4 x 16B/thread)
  auto stageA = [&](int slot, int t) {
    #pragma unroll
    for (int g = 0; g < 2; ++g)
      #pragma unroll
      for (int j = 0; j < 2; ++j) {
        int off = j * 2048 + tid * 8;
        __builtin_amdgcn_global_load_lds(
          (const __attribute__((address_space(1))) void*)(const void*)(aT + (((size_t)(2 * t + g)) << 12) + off),
          (__attribute__((address_space(3))) void*)(void*)(&AS[slot][g * 4096 + off]), 16, 0, 0);
      }
  };

  bf16x8 bX[4], bY[4];   // [g*2+ki] for K-step's two granules
  auto loadB = [&](bf16x8 (&dst)[4], int t) {
    #pragma unroll
    for (int g = 0; g < 2; ++g)
      #pragma unroll
      for (int ki = 0; ki < 2; ++ki)
        dst[g * 2 + ki] = *(const bf16x8*)(bT + (((size_t)(2 * t + g)) << 12) + boff[ki]);
  };

#define VMFENCE(N) { asm volatile("s_waitcnt vmcnt(" #N ")" ::: "memory"); \
                     __builtin_amdgcn_sched_barrier(0); }
#define LKFENCE    { asm volatile("s_waitcnt lgkmcnt(0)" ::: "memory"); \
                     __builtin_amdgcn_sched_barrier(0); }
#define BARRIER    { __builtin_amdgcn_s_barrier(); __builtin_amdgcn_sched_barrier(0); }

  // iter t: readA(g0) -> MFMA(g0) [reg-dep, pre-barrier] -> readA(g1) -> loadB(t+1)
  //         -> lgkm(0) -> stageA(t+2) -> vmcnt(8) -> barrier -> MFMA(g1)
  // RAW(A): vmcnt(8) leaves B(t+1)x4 + A(t+2)x4 outstanding (in-order) => A(t+1) landed.
  // RAW(B): compiler inserts vmcnt for B register deps.
  // WAR(A): stage at iter t writes slot (t+2)%3=(t-1)%3 whose reads finished before BAR(t-1).
  // Stagger: kt consumed at iter t is KT(t); ledger is positional, unchanged.
#define KBODY(SLOT, T, SSLOT, BC, BN)                                      \
  {                                                                        \
    bf16x8 af[4][2];                                                       \
    _Pragma("unroll")                                                      \
    for (int mf = 0; mf < 4; ++mf)                                         \
      _Pragma("unroll")                                                    \
      for (int ki = 0; ki < 2; ++ki)                                       \
        af[mf][ki] = *(const bf16x8*)&AS[SLOT][offA[mf][ki]];              \
    __builtin_amdgcn_s_setprio(1);                                         \
    _Pragma("unroll")                                                      \
    for (int ki = 0; ki < 2; ++ki)                                         \
      _Pragma("unroll")                                                    \
      for (int mf = 0; mf < 4; ++mf)                                       \
        acc[mf] = __builtin_amdgcn_mfma_f32_32x32x16_bf16(                 \
            af[mf][ki], BC[ki], acc[mf], 0, 0, 0);                         \
    __builtin_amdgcn_s_setprio(0);                                         \
    _Pragma("unroll")                                                      \
    for (int mf = 0; mf < 4; ++mf)                                         \
      _Pragma("unroll")                                                    \
      for (int ki = 0; ki < 2; ++ki)                                       \
        af[mf][ki] = *(const bf16x8*)&AS[SLOT][4096 + offA[mf][ki]];       \
    loadB(BN, KT((T) + 1));                                                \
    LKFENCE                                                                \
    stageA((SSLOT), KT((T) + 2));                                          \
    VMFENCE(8)                                                             \
    BARRIER                                                                \
    __builtin_amdgcn_s_setprio(1);                                         \
    _Pragma("unroll")                                                      \
    for (int ki = 0; ki < 2; ++ki)                                         \
      _Pragma("unroll")                                                    \
      for (int mf = 0; mf < 4; ++mf)                                       \
        acc[mf] = __builtin_amdgcn_mfma_f32_32x32x16_bf16(                 \
            af[mf][ki], BC[2 + ki], acc[mf], 0, 0, 0);                     \
    __builtin_amdgcn_s_setprio(0);                                         \
  }

  // prologue: A(KT0),A(KT1) staged (8 loads); B(KT0)->bX (4); vmcnt(8) => A(KT0) landed
  stageA(0, KT(0));
  stageA(1, KT(1));
  loadB(bX, KT(0));
  VMFENCE(8)
  BARRIER

  #pragma unroll 1
  for (int t = 0; t < 12; t += 6) {
    KBODY(0, t,     2, bX, bY)
    KBODY(1, t + 1, 0, bY, bX)
    KBODY(2, t + 2, 1, bX, bY)
    KBODY(0, t + 3, 2, bY, bX)
    KBODY(1, t + 4, 0, bX, bY)
    KBODY(2, t + 5, 1, bY, bX)
  }
  KBODY(0, 12, 2, bX, bY)
  KBODY(1, 13, 0, bY, bX)
#undef KBODY
  // tail t=14 (slot 2, B in bX): loadB(KT15)->bY; no stage; vmcnt(4) => A(KT15)+B(KT14) landed
  {
    bf16x8 af[4][2];
    #pragma unroll
    for (int mf = 0; mf < 4; ++mf)
      #pragma unroll
      for (int ki = 0; ki < 2; ++ki)
        af[mf][ki] = *(const bf16x8*)&AS[2][offA[mf][ki]];
    __builtin_amdgcn_s_setprio(1);
    #pragma unroll
    for (int ki = 0; ki < 2; ++ki)
      #pragma unroll
      for (int mf = 0; mf < 4; ++mf)
        acc[mf] = __builtin_amdgcn_mfma_f32_32x32x16_bf16(af[mf][ki], bX[ki], acc[mf], 0, 0, 0);
    __builtin_amdgcn_s_setprio(0);
    #pragma unroll
    for (int mf = 0; mf < 4; ++mf)
      #pragma unroll
      for (int ki = 0; ki < 2; ++ki)
        af[mf][ki] = *(const bf16x8*)&AS[2][4096 + offA[mf][ki]];
    loadB(bY, KT(15));
    LKFENCE
    VMFENCE(4)
    BARRIER
    __builtin_amdgcn_s_setprio(1);
    #pragma unroll
    for (int ki = 0; ki < 2; ++ki)
      #pragma unroll
      for (int mf = 0; mf < 4; ++mf)
        acc[mf] = __builtin_amdgcn_mfma_f32_32x32x16_bf16(af[mf][ki], bX[2 + ki], acc[mf], 0, 0, 0);
    __builtin_amdgcn_s_setprio(0);
  }
  // tail t=15 (slot 0, B in bY); compiler inserts lgkm/vmcnt for deps
  {
    bf16x8 af[4][2];
    #pragma unroll
    for (int mf = 0; mf < 4; ++mf)
      #pragma unroll
      for (int ki = 0; ki < 2; ++ki)
        af[mf][ki] = *(const bf16x8*)&AS[0][offA[mf][ki]];
    #pragma unroll
    for (int ki = 0; ki < 2; ++ki)
      #pragma unroll
      for (int mf = 0; mf < 4; ++mf)
        acc[mf] = __builtin_amdgcn_mfma_f32_32x32x16_bf16(af[mf][ki], bY[ki], acc[mf], 0, 0, 0);
    #pragma unroll
    for (int mf = 0; mf < 4; ++mf)
      #pragma unroll
      for (int ki = 0; ki < 2; ++ki)
        af[mf][ki] = *(const bf16x8*)&AS[0][4096 + offA[mf][ki]];
    #pragma unroll
    for (int ki = 0; ki < 2; ++ki)
      #pragma unroll
      for (int mf = 0; mf < 4; ++mf)
        acc[mf] = __builtin_amdgcn_mfma_f32_32x32x16_bf16(af[mf][ki], bY[2 + ki], acc[mf], 0, 0, 0);
  }
#undef KT

  // ---- epilogue: p[row] = sum_d v[d]*tanh(acc + dh); 64-value butterfly reduce ----
  // C layout: col = wv*32 + l31, row = mf*32 + (reg&3) + 8*(reg>>2) + 4*l5
  __syncthreads();                     // all LDS reads done; reuse AS[0] for sc
  float* sc = (float*)AS;              // [128][4] floats (2 KB)
  float vvs, dds;
  {
    int dcol = nt * 128 + wv * 32 + l31;
    vvs = v[dcol];
    dds = dh[(b << 10) + dcol];
  }
  float val[64];
  #pragma unroll
  for (int mf = 0; mf < 4; ++mf) {
    #pragma unroll
    for (int reg = 0; reg < 16; ++reg) {
      float x = acc[mf][reg] + dds;
      float e = __expf(2.0f * x);                 // tanh(x) = 1 - 2/(e^{2x}+1)
      float t = 1.0f - __fdividef(2.0f, e + 1.0f);
      val[mf * 16 + reg] = vvs * t;
    }
  }
  // simultaneous reduce over the 32 col-lanes; lane l31 ends with value idx 2*l31 (+1)
#define RSTAGE(M, HALF)                                          \
  _Pragma("unroll")                                              \
  for (int j = 0; j < (HALF); ++j) {                             \
    float keep = (l31 & (M)) ? val[(HALF) + j] : val[j];         \
    float send = (l31 & (M)) ? val[j] : val[(HALF) + j];         \
    val[j] = keep + __shfl_xor(send, (M));                       \
  }
  RSTAGE(16, 32) RSTAGE(8, 16) RSTAGE(4, 8) RSTAGE(2, 4) RSTAGE(1, 2)
#undef RSTAGE
  {
    // value v: mf = v>>4, reg = v&15 -> row = (v>>4)*32 + (v&3) + 8*((v>>2)&3) + 4*l5
    int v0 = 2 * l31;
    int row0 = ((v0 >> 4) << 5) + (v0 & 3) + (((v0 >> 2) & 3) << 3) + (l5 << 2);
    int v1 = v0 + 1;
    int row1 = ((v1 >> 4) << 5) + (v1 & 3) + (((v1 >> 2) & 3) << 3) + (l5 << 2);
    sc[row0 * 4 + wv] = val[0];
    sc[row1 * 4 + wv] = val[1];
  }
  __syncthreads();
  if (tid < 128) {
    int i = mt * 128 + tid;
    if (i < n)
      pscores[(((size_t)nt) << 16) + (b << 11) + i] =
        sc[tid * 4 + 0] + sc[tid * 4 + 1] + sc[tid * 4 + 2] + sc[tid * 4 + 3];
  }
}

// ---------------- softmax over compacted scores (8 partials); scatter weights ----------------
__global__ void softmax4_k(const float* __restrict__ ps, const int* __restrict__ rows,
                           const int* __restrict__ cnt, float* __restrict__ wout,
                           float* __restrict__ wc) {
  int b = blockIdx.x;
  int tid = threadIdx.x;
  int n = cnt[b];
  float val[8];
  float m = -INFINITY;
  #pragma unroll
  for (int ii = 0; ii < 8; ++ii) {
    int i = tid + ii * 256;
    float s = -INFINITY;
    if (i < n) {
      s = 0.f;
      #pragma unroll
      for (int nt = 0; nt < 8; ++nt) s += ps[(((size_t)nt) << 16) + (b << 11) + i];
    }
    val[ii] = s;
    m = fmaxf(m, s);
  }
  #pragma unroll
  for (int off = 1; off < 64; off <<= 1) m = fmaxf(m, __shfl_xor(m, off));
  __shared__ float r1[4], r2[4];
  if ((tid & 63) == 0) r1[tid >> 6] = m;
  __syncthreads();
  m = fmaxf(fmaxf(r1[0], r1[1]), fmaxf(r1[2], r1[3]));
  float ssum = 0.f;
  #pragma unroll
  for (int ii = 0; ii < 8; ++ii) { val[ii] = __expf(val[ii] - m); ssum += val[ii]; }
  #pragma unroll
  for (int off = 1; off < 64; off <<= 1) ssum += __shfl_xor(ssum, off);
  if ((tid & 63) == 0) r2[tid >> 6] = ssum;
  __syncthreads();
  ssum = r2[0] + r2[1] + r2[2] + r2[3];
  float inv = 1.0f / ssum;
  #pragma unroll
  for (int ii = 0; ii < 8; ++ii) {
    int i = tid + ii * 256;
    if (i < n) {
      float w = val[ii] * inv;
      wc[(b << 11) + i] = w;
      wout[((size_t)b << 11) + rows[(b << 11) + i]] = w;
    }
  }
}

// ---------------- context partials from bf16 granules [b][mt(16)] ----------------
__global__ void ctx8_k(const unsigned short* __restrict__ encP, const float* __restrict__ wc,
                       const int* __restrict__ cnt, float* __restrict__ cp) {
  int b = blockIdx.x >> 4, mt = blockIdx.x & 15;
  int n = cnt[b];
  float* out = cp + (((size_t)(b * 16 + mt)) << 10);
  int tid = threadIdx.x;
  if (mt * 128 >= n) {
    #pragma unroll
    for (int j = 0; j < 4; ++j) out[tid * 4 + j] = 0.f;
    return;
  }
  __shared__ float sw[128];
  __shared__ float red[128][8];
  if (tid < 128) {
    int i = mt * 128 + tid;
    sw[tid] = (i < n) ? wc[(b << 11) + i] : 0.f;
  }
  __syncthreads();
  const unsigned short* tile = encP + (((size_t)(b * 16 + mt)) << 17);
  int cb8  = tid & 127;          // 8-col block: kt = cb8>>3, kb = cb8&7
  int half = tid >> 7;           // rows 0-63 / 64-127
  const unsigned short* base = tile + ((cb8 >> 3) << 13) + ((cb8 & 7) << 10);
  float a[8];
  #pragma unroll
  for (int j = 0; j < 8; ++j) a[j] = 0.f;
  for (int rr = 0; rr < 64; ++rr) {
    int r = half * 64 + rr;
    float w = sw[r];
    ushort8 u = *(const ushort8*)(base + (r << 3));
    #pragma unroll
    for (int j = 0; j < 8; ++j) a[j] += w * bf2f(u[j]);
  }
  if (half == 1) {
    #pragma unroll
    for (int j = 0; j < 8; ++j) red[cb8][j] = a[j];
  }
  __syncthreads();
  if (half == 0) {
    #pragma unroll
    for (int j = 0; j < 8; ++j) out[cb8 * 8 + j] = a[j] + red[cb8][j];
  }
}

__global__ void ctx_red4_k(const float* __restrict__ cp, float* __restrict__ out) {
  int t = blockIdx.x * 256 + threadIdx.x;   // 32768
  int b = t >> 10, e = t & 1023;
  float a = 0.f;
  #pragma unroll
  for (int mt = 0; mt < 16; ++mt) a += cp[(((size_t)(b * 16 + mt)) << 10) + e];
  out[t] = a;
}

extern "C" void kernel_launch(void* const* d_in, const int* in_sizes, int n_in,
                              void* d_out, int out_size, void* d_ws, size_t ws_size,
                              hipStream_t stream) {
  const float* dec  = (const float*)d_in[0];
  const float* enc  = (const float*)d_in[1];
  const int*   mask = (const int*)d_in[2];
  const float* Wenc = (const float*)d_in[3];
  const float* Wdec = (const float*)d_in[4];
  const float* v    = (const float*)d_in[5];
  float* out_ctx = (float*)d_out;                 // [32][1024]
  float* out_w   = (float*)d_out + 32768;         // [32][2048]

  char* ws = (char*)d_ws;
  unsigned short* Wt = (unsigned short*)ws;                       // 2 MB  bf16 W_enc granules
  float* dh    = (float*)(ws + (2u << 20));                       // 128 KB
  int*   rows  = (int*)(ws + (2u << 20) + (128u << 10));          // 256 KB
  float* wc    = (float*)(ws + (2u << 20) + (384u << 10));        // 256 KB
  int*   cnt   = (int*)(ws + (2u << 20) + (640u << 10));          // 4 KB
  float* pscores = (float*)(ws + (3u << 20));                     // 2 MB  [8][32][2048]
  float* cp      = (float*)(ws + (5u << 20));                     // 2 MB  [32][16][1024]
  unsigned short* encP = (unsigned short*)(ws + (8ull << 20));    // 128 MB packed enc granules

  hipLaunchKernelGGL(prep_fused_k, dim3(672),  dim3(256), 0, stream, Wenc, Wt, dec, Wdec, dh,
                     mask, rows, cnt, out_w);
  hipLaunchKernelGGL(pack8_k,      dim3(512),  dim3(256), 0, stream, enc, rows, cnt, encP);
  hipLaunchKernelGGL(score15_k,    dim3(4096), dim3(256), 0, stream, encP, Wt, dh, v, cnt, pscores);
  hipLaunchKernelGGL(softmax4_k,   dim3(32),   dim3(256), 0, stream, pscores, rows, cnt, out_w, wc);
  hipLaunchKernelGGL(ctx8_k,       dim3(512),  dim3(256), 0, stream, encP, wc, cnt, cp);
  hipLaunchKernelGGL(ctx_red4_k,   dim3(128),  dim3(256), 0, stream, cp, out_ctx);
}

// Round 16
// 187.299 us; speedup vs baseline: 1.0266x; 1.0266x over previous
//
#include <hip/hip_runtime.h>
#include <stdint.h>

typedef float f32x4 __attribute__((ext_vector_type(4)));
typedef float f32x16 __attribute__((ext_vector_type(16)));
typedef short bf16x8 __attribute__((ext_vector_type(8)));
typedef unsigned short ushort8 __attribute__((ext_vector_type(8)));

__device__ __forceinline__ unsigned short f2bf(float x) {
  union { float f; uint32_t u; } c; c.f = x;
  return (unsigned short)((c.u + 0x8000u) >> 16);
}
__device__ __forceinline__ float bf2f(unsigned short u) {
  union { uint32_t u; float f; } c; c.u = ((uint32_t)u) << 16;
  return c.f;
}

// Granule layout: per tile 131072 shorts = [kt(32)][kb4(4)][r(128)][e(8)]
// MFMA 32x32x16 frag read (lane l, ki): r = base+(l&31), kb4 = ki*2+(l>>5)
//   -> consecutive lanes touch consecutive 16B (LDS conflict-free / gmem coalesced).
// score14 consumes TWO granules (kt=2t, 2t+1) per barrier pair (BK=64).

// ---------------- fused prep: W_enc granules ; dh ; mask compaction ----------------
__global__ void prep_fused_k(const float* __restrict__ W, unsigned short* __restrict__ Wt,
                             const float* __restrict__ dec, const float* __restrict__ Wd,
                             float* __restrict__ dh, const int* __restrict__ mask,
                             int* __restrict__ rows, int* __restrict__ cnt,
                             float* __restrict__ wout) {
  if (blockIdx.x < 512) {
    int t = blockIdx.x * 256 + threadIdx.x;      // 131072
    int d  = t >> 7;                              // 0..1023 (output dim = granule row)
    int c0 = (t & 127) << 3;
    const float* src = W + ((size_t)d << 10) + c0;
    f32x4 f0 = *(const f32x4*)src;
    f32x4 f1 = *(const f32x4*)(src + 4);
    ushort8 u;
    u[0]=f2bf(f0[0]); u[1]=f2bf(f0[1]); u[2]=f2bf(f0[2]); u[3]=f2bf(f0[3]);
    u[4]=f2bf(f1[0]); u[5]=f2bf(f1[1]); u[6]=f2bf(f1[2]); u[7]=f2bf(f1[3]);
    int nt = d >> 7, r = d & 127;
    int kt = c0 >> 6, kb = (c0 & 63) >> 3;
    *(ushort8*)(Wt + ((size_t)nt << 17) + (kt << 13) + ((kb * 128 + r) << 3)) = u;
  } else if (blockIdx.x < 640) {
    __shared__ float sdec[1024];
    int bb = blockIdx.x - 512;
    int b = bb >> 2;
    for (int i = threadIdx.x; i < 1024; i += 256) sdec[i] = dec[(b << 10) + i];
    __syncthreads();
    int d = ((bb & 3) << 8) + threadIdx.x;
    const float* wr = Wd + ((size_t)d << 10);
    float a = 0.f;
    for (int k = 0; k < 1024; k += 4) {
      f32x4 wv = *(const f32x4*)(wr + k);
      f32x4 xv = *(const f32x4*)(&sdec[k]);
      a += wv[0]*xv[0] + wv[1]*xv[1] + wv[2]*xv[2] + wv[3]*xv[3];
    }
    dh[(b << 10) + d] = a;
  } else {
    int b = blockIdx.x - 640, tid = threadIdx.x;
    int lane = tid & 63, wvx = tid >> 6;
    int mloc[8]; int c = 0;
    #pragma unroll
    for (int ii = 0; ii < 8; ++ii) {
      int s = tid * 8 + ii;
      int m = mask[(b << 11) + s];
      mloc[ii] = m; c += m;
      wout[(b << 11) + s] = 0.f;
    }
    int inc = c;
    #pragma unroll
    for (int off = 1; off < 64; off <<= 1) {
      int nn = __shfl_up(inc, off);
      if (lane >= off) inc += nn;
    }
    __shared__ int wsum[4];
    if (lane == 63) wsum[wvx] = inc;
    __syncthreads();
    int base = 0;
    for (int w = 0; w < wvx; ++w) base += wsum[w];
    int idx = base + inc - c;
    #pragma unroll
    for (int ii = 0; ii < 8; ++ii) {
      if (mloc[ii]) { rows[(b << 11) + idx] = tid * 8 + ii; ++idx; }
    }
    if (tid == 0) cnt[b] = wsum[0] + wsum[1] + wsum[2] + wsum[3];
  }
}

// ---------------- pack: enc rows -> granules, LDS-transposed so BOTH sides coalesce ----------------
__global__ void pack8_k(const float* __restrict__ enc, const int* __restrict__ rows,
                        const int* __restrict__ cnt, unsigned short* __restrict__ encP) {
  int b = blockIdx.x >> 4, mt = blockIdx.x & 15;
  int n = cnt[b];
  if (mt * 128 >= n) return;
  __shared__ int sr[128];
  __shared__ unsigned short T[128 * 64];   // bf16 tile, col-block swizzled
  int tid = threadIdx.x;
  if (tid < 128) {
    int i = mt * 128 + tid; if (i >= n) i = n - 1;
    sr[tid] = rows[(b << 11) + i];
  }
  __syncthreads();
  unsigned short* dst = encP + (((size_t)(b * 16 + mt)) << 17);
  for (int kt = 0; kt < 16; ++kt) {
    #pragma unroll
    for (int p = 0; p < 4; ++p) {
      int id = p * 256 + tid;            // 0..1023
      int r = id >> 3, cseg = id & 7;    // cseg: 8-col block
      const float* src = enc + (((size_t)(b << 11) + sr[r]) << 10) + (kt << 6) + (cseg << 3);
      f32x4 f0 = *(const f32x4*)src;
      f32x4 f1 = *(const f32x4*)(src + 4);
      ushort8 u;
      u[0]=f2bf(f0[0]); u[1]=f2bf(f0[1]); u[2]=f2bf(f0[2]); u[3]=f2bf(f0[3]);
      u[4]=f2bf(f1[0]); u[5]=f2bf(f1[1]); u[6]=f2bf(f1[2]); u[7]=f2bf(f1[3]);
      *(ushort8*)&T[(r << 6) + ((cseg ^ (r & 7)) << 3)] = u;
    }
    __syncthreads();
    unsigned short* g = dst + (kt << 13);
    #pragma unroll
    for (int p = 0; p < 4; ++p) {
      int blk = p * 256 + tid;           // 0..1023
      int kb = blk >> 7, r = blk & 127;
      ushort8 u = *(const ushort8*)&T[(r << 6) + ((kb ^ (r & 7)) << 3)];
      *(ushort8*)(g + (blk << 3)) = u;
    }
    __syncthreads();
  }
}

// ---------------- main fused GEMM: BK=64, A ring-3 LDS (16KB slots) + B-dedup regs ----------------
// Wave tile 128x32; 16 barrier pairs (r14 structure, measured best).
__global__ __launch_bounds__(256, 3) void score14_k(
    const unsigned short* __restrict__ encP, const unsigned short* __restrict__ Wt,
    const float* __restrict__ dh, const float* __restrict__ v,
    const int* __restrict__ cnt, float* __restrict__ pscores)
{
  // XCD swizzle: 8 consecutive same-XCD ids share one A-tile (sweep nt fastest)
  int L  = (blockIdx.x & 7) * 512 + (blockIdx.x >> 3);   // bijective, 4096 = 8*512
  int b  = L >> 7, mt = (L >> 3) & 15, nt = L & 7;
  int n  = cnt[b];
  if (mt * 128 >= n) return;

  __shared__ __align__(16) unsigned short AS[3][8192];   // 3 x 16 KB (A, 2 granules/slot)

  int tid  = threadIdx.x;
  int lane = tid & 63;
  int wv   = tid >> 6;                  // wave owns cols wv*32..wv*32+31
  int l31 = lane & 31, l5 = lane >> 5;

  const unsigned short* aT = encP + (((size_t)(b * 16 + mt)) << 17);
  const unsigned short* bT = Wt + ((size_t)nt << 17);

  // per-granule frag offsets (elems): kb4 = ki*2+l5
  int offA[4][2], boff[2];
  #pragma unroll
  for (int mf = 0; mf < 4; ++mf) {
    int r = mf * 32 + l31;
    #pragma unroll
    for (int ki = 0; ki < 2; ++ki)
      offA[mf][ki] = (((ki * 2 + l5) << 7) + r) << 3;
  }
  {
    int r = wv * 32 + l31;
    #pragma unroll
    for (int ki = 0; ki < 2; ++ki)
      boff[ki] = (((ki * 2 + l5) << 7) + r) << 3;
  }

  f32x16 acc[4];
  #pragma unroll
  for (int i = 0; i < 4; ++i)
    #pragma unroll
    for (int e = 0; e < 16; ++e)
      acc[i][e] = 0.f;

  // stage both granules of K-step t into slot (4 x 16B/thread)
  auto stageA = [&](int slot, int t) {
    #pragma unroll
    for (int g = 0; g < 2; ++g)
      #pragma unroll
      for (int j = 0; j < 2; ++j) {
        int off = j * 2048 + tid * 8;
        __builtin_amdgcn_global_load_lds(
          (const __attribute__((address_space(1))) void*)(const void*)(aT + (((size_t)(2 * t + g)) << 12) + off),
          (__attribute__((address_space(3))) void*)(void*)(&AS[slot][g * 4096 + off]), 16, 0, 0);
      }
  };

  bf16x8 bX[4], bY[4];   // [g*2+ki] for K-step's two granules
  auto loadB = [&](bf16x8 (&dst)[4], int t) {
    #pragma unroll
    for (int g = 0; g < 2; ++g)
      #pragma unroll
      for (int ki = 0; ki < 2; ++ki)
        dst[g * 2 + ki] = *(const bf16x8*)(bT + (((size_t)(2 * t + g)) << 12) + boff[ki]);
  };

#define VMFENCE(N) { asm volatile("s_waitcnt vmcnt(" #N ")" ::: "memory"); \
                     __builtin_amdgcn_sched_barrier(0); }
#define LKFENCE    { asm volatile("s_waitcnt lgkmcnt(0)" ::: "memory"); \
                     __builtin_amdgcn_sched_barrier(0); }
#define BARRIER    { __builtin_amdgcn_s_barrier(); __builtin_amdgcn_sched_barrier(0); }

  // iter t: readA(g0) -> MFMA(g0) [reg-dep, pre-barrier] -> readA(g1) -> loadB(t+1)
  //         -> lgkm(0) -> stageA(t+2) -> vmcnt(8) -> barrier -> MFMA(g1)
  // RAW(A): vmcnt(8) leaves B(t+1)x4 + A(t+2)x4 outstanding (in-order) => A(t+1) landed.
  // RAW(B): compiler inserts vmcnt for B register deps.
  // WAR(A): stage at iter t writes slot (t+2)%3=(t-1)%3 whose reads finished before BAR(t-1).
#define KBODY(SLOT, T, SSLOT, BC, BN)                                      \
  {                                                                        \
    bf16x8 af[4][2];                                                       \
    _Pragma("unroll")                                                      \
    for (int mf = 0; mf < 4; ++mf)                                         \
      _Pragma("unroll")                                                    \
      for (int ki = 0; ki < 2; ++ki)                                       \
        af[mf][ki] = *(const bf16x8*)&AS[SLOT][offA[mf][ki]];              \
    _Pragma("unroll")                                                      \
    for (int ki = 0; ki < 2; ++ki)                                         \
      _Pragma("unroll")                                                    \
      for (int mf = 0; mf < 4; ++mf)                                       \
        acc[mf] = __builtin_amdgcn_mfma_f32_32x32x16_bf16(                 \
            af[mf][ki], BC[ki], acc[mf], 0, 0, 0);                         \
    _Pragma("unroll")                                                      \
    for (int mf = 0; mf < 4; ++mf)                                         \
      _Pragma("unroll")                                                    \
      for (int ki = 0; ki < 2; ++ki)                                       \
        af[mf][ki] = *(const bf16x8*)&AS[SLOT][4096 + offA[mf][ki]];       \
    loadB(BN, (T) + 1);                                                    \
    LKFENCE                                                                \
    stageA((SSLOT), (T) + 2);                                              \
    VMFENCE(8)                                                             \
    BARRIER                                                                \
    _Pragma("unroll")                                                      \
    for (int ki = 0; ki < 2; ++ki)                                         \
      _Pragma("unroll")                                                    \
      for (int mf = 0; mf < 4; ++mf)                                       \
        acc[mf] = __builtin_amdgcn_mfma_f32_32x32x16_bf16(                 \
            af[mf][ki], BC[2 + ki], acc[mf], 0, 0, 0);                     \
  }

  // prologue: A(0),A(1) staged (8 loads); B(0)->bX (4); vmcnt(8) => A(0) landed
  stageA(0, 0);
  stageA(1, 1);
  loadB(bX, 0);
  VMFENCE(8)
  BARRIER

  #pragma unroll 1
  for (int t = 0; t < 12; t += 6) {
    KBODY(0, t,     2, bX, bY)
    KBODY(1, t + 1, 0, bY, bX)
    KBODY(2, t + 2, 1, bX, bY)
    KBODY(0, t + 3, 2, bY, bX)
    KBODY(1, t + 4, 0, bX, bY)
    KBODY(2, t + 5, 1, bY, bX)
  }
  KBODY(0, 12, 2, bX, bY)
  KBODY(1, 13, 0, bY, bX)
#undef KBODY
  // tail t=14 (slot 2, B in bX): loadB(15)->bY; no stage; vmcnt(4) => A(15)+B(14) landed
  {
    bf16x8 af[4][2];
    #pragma unroll
    for (int mf = 0; mf < 4; ++mf)
      #pragma unroll
      for (int ki = 0; ki < 2; ++ki)
        af[mf][ki] = *(const bf16x8*)&AS[2][offA[mf][ki]];
    #pragma unroll
    for (int ki = 0; ki < 2; ++ki)
      #pragma unroll
      for (int mf = 0; mf < 4; ++mf)
        acc[mf] = __builtin_amdgcn_mfma_f32_32x32x16_bf16(af[mf][ki], bX[ki], acc[mf], 0, 0, 0);
    #pragma unroll
    for (int mf = 0; mf < 4; ++mf)
      #pragma unroll
      for (int ki = 0; ki < 2; ++ki)
        af[mf][ki] = *(const bf16x8*)&AS[2][4096 + offA[mf][ki]];
    loadB(bY, 15);
    LKFENCE
    VMFENCE(4)
    BARRIER
    #pragma unroll
    for (int ki = 0; ki < 2; ++ki)
      #pragma unroll
      for (int mf = 0; mf < 4; ++mf)
        acc[mf] = __builtin_amdgcn_mfma_f32_32x32x16_bf16(af[mf][ki], bX[2 + ki], acc[mf], 0, 0, 0);
  }
  // tail t=15 (slot 0, B in bY); compiler inserts lgkm/vmcnt for deps
  {
    bf16x8 af[4][2];
    #pragma unroll
    for (int mf = 0; mf < 4; ++mf)
      #pragma unroll
      for (int ki = 0; ki < 2; ++ki)
        af[mf][ki] = *(const bf16x8*)&AS[0][offA[mf][ki]];
    #pragma unroll
    for (int ki = 0; ki < 2; ++ki)
      #pragma unroll
      for (int mf = 0; mf < 4; ++mf)
        acc[mf] = __builtin_amdgcn_mfma_f32_32x32x16_bf16(af[mf][ki], bY[ki], acc[mf], 0, 0, 0);
    #pragma unroll
    for (int mf = 0; mf < 4; ++mf)
      #pragma unroll
      for (int ki = 0; ki < 2; ++ki)
        af[mf][ki] = *(const bf16x8*)&AS[0][4096 + offA[mf][ki]];
    #pragma unroll
    for (int ki = 0; ki < 2; ++ki)
      #pragma unroll
      for (int mf = 0; mf < 4; ++mf)
        acc[mf] = __builtin_amdgcn_mfma_f32_32x32x16_bf16(af[mf][ki], bY[2 + ki], acc[mf], 0, 0, 0);
  }

  // ---- epilogue: p[row] = sum_d v[d]*tanh(acc + dh); 64-value butterfly reduce ----
  // C layout: col = wv*32 + l31, row = mf*32 + (reg&3) + 8*(reg>>2) + 4*l5
  __syncthreads();                     // all LDS reads done; reuse AS[0] for sc
  float* sc = (float*)AS;              // [128][4] floats (2 KB)
  float vvs, dds;
  {
    int dcol = nt * 128 + wv * 32 + l31;
    vvs = v[dcol];
    dds = dh[(b << 10) + dcol];
  }
  float val[64];
  #pragma unroll
  for (int mf = 0; mf < 4; ++mf) {
    #pragma unroll
    for (int reg = 0; reg < 16; ++reg) {
      float x = acc[mf][reg] + dds;
      float e = __expf(2.0f * x);                 // tanh(x) = 1 - 2/(e^{2x}+1)
      float t = 1.0f - __fdividef(2.0f, e + 1.0f);
      val[mf * 16 + reg] = vvs * t;
    }
  }
  // simultaneous reduce over the 32 col-lanes; lane l31 ends with value idx 2*l31 (+1)
#define RSTAGE(M, HALF)                                          \
  _Pragma("unroll")                                              \
  for (int j = 0; j < (HALF); ++j) {                             \
    float keep = (l31 & (M)) ? val[(HALF) + j] : val[j];         \
    float send = (l31 & (M)) ? val[j] : val[(HALF) + j];         \
    val[j] = keep + __shfl_xor(send, (M));                       \
  }
  RSTAGE(16, 32) RSTAGE(8, 16) RSTAGE(4, 8) RSTAGE(2, 4) RSTAGE(1, 2)
#undef RSTAGE
  {
    // value v: mf = v>>4, reg = v&15 -> row = (v>>4)*32 + (v&3) + 8*((v>>2)&3) + 4*l5
    int v0 = 2 * l31;
    int row0 = ((v0 >> 4) << 5) + (v0 & 3) + (((v0 >> 2) & 3) << 3) + (l5 << 2);
    int v1 = v0 + 1;
    int row1 = ((v1 >> 4) << 5) + (v1 & 3) + (((v1 >> 2) & 3) << 3) + (l5 << 2);
    sc[row0 * 4 + wv] = val[0];
    sc[row1 * 4 + wv] = val[1];
  }
  __syncthreads();
  if (tid < 128) {
    int i = mt * 128 + tid;
    if (i < n)
      pscores[(((size_t)nt) << 16) + (b << 11) + i] =
        sc[tid * 4 + 0] + sc[tid * 4 + 1] + sc[tid * 4 + 2] + sc[tid * 4 + 3];
  }
}

// ---------------- softmax over compacted scores (8 partials), 512 threads ----------------
__global__ void softmax5_k(const float* __restrict__ ps, const int* __restrict__ rows,
                           const int* __restrict__ cnt, float* __restrict__ wout,
                           float* __restrict__ wc) {
  int b = blockIdx.x;
  int tid = threadIdx.x;            // 0..511
  int n = cnt[b];
  float val[4];
  float m = -INFINITY;
  #pragma unroll
  for (int ii = 0; ii < 4; ++ii) {
    int i = tid + ii * 512;
    float s = -INFINITY;
    if (i < n) {
      s = 0.f;
      #pragma unroll
      for (int nt = 0; nt < 8; ++nt) s += ps[(((size_t)nt) << 16) + (b << 11) + i];
    }
    val[ii] = s;
    m = fmaxf(m, s);
  }
  #pragma unroll
  for (int off = 1; off < 64; off <<= 1) m = fmaxf(m, __shfl_xor(m, off));
  __shared__ float r1[8], r2[8];
  if ((tid & 63) == 0) r1[tid >> 6] = m;
  __syncthreads();
  m = r1[0];
  #pragma unroll
  for (int w = 1; w < 8; ++w) m = fmaxf(m, r1[w]);
  float ssum = 0.f;
  #pragma unroll
  for (int ii = 0; ii < 4; ++ii) { val[ii] = __expf(val[ii] - m); ssum += val[ii]; }
  #pragma unroll
  for (int off = 1; off < 64; off <<= 1) ssum += __shfl_xor(ssum, off);
  if ((tid & 63) == 0) r2[tid >> 6] = ssum;
  __syncthreads();
  ssum = 0.f;
  #pragma unroll
  for (int w = 0; w < 8; ++w) ssum += r2[w];
  float inv = 1.0f / ssum;
  #pragma unroll
  for (int ii = 0; ii < 4; ++ii) {
    int i = tid + ii * 512;
    if (i < n) {
      float w = val[ii] * inv;
      wc[(b << 11) + i] = w;
      wout[((size_t)b << 11) + rows[(b << 11) + i]] = w;
    }
  }
}

// ---------------- context partials from bf16 granules [b][mt(16)] ----------------
__global__ void ctx8_k(const unsigned short* __restrict__ encP, const float* __restrict__ wc,
                       const int* __restrict__ cnt, float* __restrict__ cp) {
  int b = blockIdx.x >> 4, mt = blockIdx.x & 15;
  int n = cnt[b];
  float* out = cp + (((size_t)(b * 16 + mt)) << 10);
  int tid = threadIdx.x;
  if (mt * 128 >= n) {
    #pragma unroll
    for (int j = 0; j < 4; ++j) out[tid * 4 + j] = 0.f;
    return;
  }
  __shared__ float sw[128];
  __shared__ float red[128][8];
  if (tid < 128) {
    int i = mt * 128 + tid;
    sw[tid] = (i < n) ? wc[(b << 11) + i] : 0.f;
  }
  __syncthreads();
  const unsigned short* tile = encP + (((size_t)(b * 16 + mt)) << 17);
  int cb8  = tid & 127;          // 8-col block: kt = cb8>>3, kb = cb8&7
  int half = tid >> 7;           // rows 0-63 / 64-127
  const unsigned short* base = tile + ((cb8 >> 3) << 13) + ((cb8 & 7) << 10);
  float a[8];
  #pragma unroll
  for (int j = 0; j < 8; ++j) a[j] = 0.f;
  #pragma unroll 4
  for (int rr = 0; rr < 64; ++rr) {
    int r = half * 64 + rr;
    float w = sw[r];
    ushort8 u = *(const ushort8*)(base + (r << 3));
    #pragma unroll
    for (int j = 0; j < 8; ++j) a[j] += w * bf2f(u[j]);
  }
  if (half == 1) {
    #pragma unroll
    for (int j = 0; j < 8; ++j) red[cb8][j] = a[j];
  }
  __syncthreads();
  if (half == 0) {
    #pragma unroll
    for (int j = 0; j < 8; ++j) out[cb8 * 8 + j] = a[j] + red[cb8][j];
  }
}

__global__ void ctx_red4_k(const float* __restrict__ cp, float* __restrict__ out) {
  int t = blockIdx.x * 256 + threadIdx.x;   // 32768
  int b = t >> 10, e = t & 1023;
  float a = 0.f;
  #pragma unroll
  for (int mt = 0; mt < 16; ++mt) a += cp[(((size_t)(b * 16 + mt)) << 10) + e];
  out[t] = a;
}

extern "C" void kernel_launch(void* const* d_in, const int* in_sizes, int n_in,
                              void* d_out, int out_size, void* d_ws, size_t ws_size,
                              hipStream_t stream) {
  const float* dec  = (const float*)d_in[0];
  const float* enc  = (const float*)d_in[1];
  const int*   mask = (const int*)d_in[2];
  const float* Wenc = (const float*)d_in[3];
  const float* Wdec = (const float*)d_in[4];
  const float* v    = (const float*)d_in[5];
  float* out_ctx = (float*)d_out;                 // [32][1024]
  float* out_w   = (float*)d_out + 32768;         // [32][2048]

  char* ws = (char*)d_ws;
  unsigned short* Wt = (unsigned short*)ws;                       // 2 MB  bf16 W_enc granules
  float* dh    = (float*)(ws + (2u << 20));                       // 128 KB
  int*   rows  = (int*)(ws + (2u << 20) + (128u << 10));          // 256 KB
  float* wc    = (float*)(ws + (2u << 20) + (384u << 10));        // 256 KB
  int*   cnt   = (int*)(ws + (2u << 20) + (640u << 10));          // 4 KB
  float* pscores = (float*)(ws + (3u << 20));                     // 2 MB  [8][32][2048]
  float* cp      = (float*)(ws + (5u << 20));                     // 2 MB  [32][16][1024]
  unsigned short* encP = (unsigned short*)(ws + (8ull << 20));    // 128 MB packed enc granules

  hipLaunchKernelGGL(prep_fused_k, dim3(672),  dim3(256), 0, stream, Wenc, Wt, dec, Wdec, dh,
                     mask, rows, cnt, out_w);
  hipLaunchKernelGGL(pack8_k,      dim3(512),  dim3(256), 0, stream, enc, rows, cnt, encP);
  hipLaunchKernelGGL(score14_k,    dim3(4096), dim3(256), 0, stream, encP, Wt, dh, v, cnt, pscores);
  hipLaunchKernelGGL(softmax5_k,   dim3(32),   dim3(512), 0, stream, pscores, rows, cnt, out_w, wc);
  hipLaunchKernelGGL(ctx8_k,       dim3(512),  dim3(256), 0, stream, encP, wc, cnt, cp);
  hipLaunchKernelGGL(ctx_red4_k,   dim3(128),  dim3(256), 0, stream, cp, out_ctx);
}